// Round 8
// baseline (81339.636 us; speedup 1.0000x reference)
//
#include <hip/hip_runtime.h>
#include <hip/hip_bf16.h>

#define B_ 1024
#define T_ 256
#define V_ 90
#define H_ 256
#define NTHR 512
#define NBLK 256
#define S_ (B_*H_)

typedef unsigned short u16;
typedef __attribute__((ext_vector_type(8))) short bf16x8;
typedef __attribute__((ext_vector_type(4))) float f32x4;
typedef __attribute__((ext_vector_type(4))) unsigned short u16x4;

// ---------------- ws layout (float offsets) ----------------
constexpr size_t OFF_GH1C  = 0;
constexpr size_t OFF_GC1C  = OFF_GH1C + S_;
constexpr size_t OFF_GH1P  = OFF_GC1C + S_;
constexpr size_t OFF_GC1P  = OFF_GH1P + S_;
constexpr size_t OFF_LH1   = OFF_GC1P + S_;      // 2 buffers
constexpr size_t OFF_LC1   = OFF_LH1 + 2*S_;
constexpr size_t OFF_GH2C  = OFF_LC1 + 2*S_;
constexpr size_t OFF_GC2C  = OFF_GH2C + S_;
constexpr size_t OFF_GH2P  = OFF_GC2C + S_;
constexpr size_t OFF_GC2P  = OFF_GH2P + S_;
constexpr size_t OFF_LH2   = OFF_GC2P + S_;      // 2 buffers
constexpr size_t OFF_LC2   = OFF_LH2 + 2*S_;
constexpr size_t OFF_MLP1A = OFF_LC2 + 2*S_;     // 1024*512
constexpr size_t OFF_MLP1B = OFF_MLP1A + (size_t)B_*512;
constexpr size_t OFF_EX    = OFF_MLP1B + (size_t)B_*512;  // 2*1024*8
// packed bf16 hi/lo weights (K*N elements -> K*N floats of storage each)
constexpr size_t OFF_WG1PK = OFF_EX + 2*B_*8;    // K=256,N=2048
constexpr size_t OFF_WE1   = OFF_WG1PK + 256*2048/1*1; // fp32 [8][2048] after pk: compute below
constexpr size_t OFF_WE1_  = OFF_WG1PK + (size_t)256*2048; // = pk floats
constexpr size_t OFF_BG1   = OFF_WE1_ + 8*2048;
constexpr size_t OFF_WL2PK = OFF_BG1 + 2048;     // K=512,N=1024
constexpr size_t OFF_BL2   = OFF_WL2PK + (size_t)512*1024;
constexpr size_t OFF_WG2PK = OFF_BL2 + 1024;
constexpr size_t OFF_BG2   = OFF_WG2PK + (size_t)512*1024;
constexpr size_t OFF_WP1PK = OFF_BG2 + 1024;     // K=1024,N=512
constexpr size_t OFF_WEP1  = OFF_WP1PK + (size_t)1024*512;
constexpr size_t OFF_WP2PK = OFF_WEP1 + 8*512;
constexpr size_t OFF_WEP2  = OFF_WP2PK + (size_t)1024*512;
constexpr size_t OFF_WB1   = OFF_WEP2 + 8*512;   // fp32 [512][256]
constexpr size_t OFF_WB2   = OFF_WB1 + 512*256;
constexpr size_t OFF_WOUT  = OFF_WB2 + 512*256;  // fp32 [256][96]
constexpr size_t OFF_BOUT  = OFF_WOUT + 256*96;
constexpr size_t OFF_BAR   = OFF_BOUT + 128;     // 8 XCD * 1024 uints
constexpr size_t WS_FLOATS = OFF_BAR + 8192;

struct InP {
  const int*   seq;
  const float* emb;
  const float *g1_Wih,*g1_Whh,*g1_bih,*g1_bhh;
  const float *g2_Wih,*g2_Whh,*g2_bih,*g2_bhh;
  const float *l1_Wih,*l1_Whh,*l1_bih,*l1_bhh;
  const float *l2_Wih,*l2_Whh,*l2_bih,*l2_bhh;
  const float *p1_W1,*p1_b1,*p1_W2,*p1_b2,*p1_W3,*p1_b3;
  const float *p2_W1,*p2_b1,*p2_W2,*p2_b2,*p2_W3,*p2_b3;
  const float *gfc_W,*gfc_b,*lfc_W,*lfc_b;
};

__device__ __forceinline__ float sig_(float x)  { return 1.f/(1.f+__expf(-x)); }
__device__ __forceinline__ float tanh_(float x) { return 1.f - 2.f/(__expf(2.f*x)+1.f); }

__device__ __forceinline__ unsigned short f2bf(float v) {
  unsigned u = __builtin_bit_cast(unsigned, v);
  u += 0x7FFFu + ((u >> 16) & 1u);
  return (unsigned short)(u >> 16);
}
__device__ __forceinline__ float bf2f(unsigned short s) {
  unsigned u = (unsigned)s << 16; return __builtin_bit_cast(float, u);
}

// ---- AGENT-scope (sc1) flag ops (R7-proven barrier) ----
__device__ __forceinline__ unsigned ld_flag(const unsigned* p) {
  unsigned v;
  asm volatile("global_load_dword %0, %1, off sc1\n\ts_waitcnt vmcnt(0)"
               : "=v"(v) : "v"(p) : "memory");
  return v;
}
__device__ __forceinline__ void st_flag(unsigned* p, unsigned v) {
  asm volatile("global_store_dword %0, %1, off sc1\n\ts_waitcnt vmcnt(0)"
               :: "v"(p), "v"(v) : "memory");
}

__device__ __forceinline__ void gbar_x(unsigned* arr, unsigned* go, int slot, unsigned ep)
{
  __syncthreads();
  if (threadIdx.x < 64) {
    if (threadIdx.x == 0) st_flag(&arr[slot*16], ep);
    if (slot == 0) {
      if (threadIdx.x < 32) {
        int cap = 0;
        for (;;) {
          unsigned v = ld_flag(&arr[threadIdx.x*16]);
          if (v >= ep) break;
          __builtin_amdgcn_s_sleep(2);
          if (++cap > 65536) break;
        }
      }
      if (threadIdx.x == 0) st_flag(go, ep);
    } else if (threadIdx.x == 0) {
      int cap = 0;
      for (;;) {
        unsigned v = ld_flag(go);
        if (v >= ep) break;
        __builtin_amdgcn_s_sleep(2);
        if (++cap > 65536) break;
      }
    }
  }
  __syncthreads();
  asm volatile("buffer_inv sc0" ::: "memory");
}

// ============ bf16x3 MFMA tile GEMM: 64 rows x 128 cols, 8 waves ============
// Waves: wr = (tid>>6)&3 (16-row strip), wc = tid>>8 (64-col half).
// Frag convention (both A and B packed with the SAME k-bijection k=(l>>4)*8+e):
//   A: lane l&15 = row, slots (l>>4, e) -> k.  B: lane l&15 = col, same slots.
//   C/D: col = l&15, row = (l>>4)*4 + reg   [HW-verified m89]
// LDS per buffer (ushorts): A_hi[4*512] A_lo[4*512] B[8 tiles][hi 512|lo 512]
template<int NCH, int NSEG, bool HASE, class FE>
__device__ __forceinline__ void mm_mfma(
    u16* sAB, float* sWe, float* sE,
    const float* s0, const float* s1_,
    const u16* Wpk, int wstep,          // block-sliced base; ushorts per chunk (full N)
    const float* WeP, int ldwe, const float* ex,
    int r0, int ct0, FE fe)
{
  constexpr int BUFU = 12288;
  const int tid = threadIdx.x;
  const int lane = tid & 63;
  const int wr = (tid >> 6) & 3, wc = tid >> 8;
  const int ar = tid >> 3, ak = (tid & 7) << 2;

  if (HASE) {
    for (int i = tid; i < 8*128; i += NTHR)
      sWe[i] = WeP[(i >> 7) * ldwe + ct0 + (i & 127)];
    sE[tid] = ex[((r0 + ar) << 3) + (tid & 7)];
  }

  f32x4 acc[4] = {{0,0,0,0},{0,0,0,0},{0,0,0,0},{0,0,0,0}};

  auto lda = [&](int c) -> float4 {
    int k0 = c * 32;
    const float* S = (NSEG == 1) ? s0 : ((k0 < 256) ? s0 : s1_);
    return *(const float4*)&S[(size_t)(r0 + ar) * H_ + (k0 & 255) + ak];
  };
  auto ldw = [&](int c, float4& w0, float4& w1) {
    const float* p = (const float*)(Wpk + (size_t)c * wstep) + tid * 8;
    w0 = *(const float4*)p; w1 = *(const float4*)(p + 4);
  };
  auto storec = [&](int pb, const float4& pa, const float4& w0, const float4& w1) {
    float vv[4] = {pa.x, pa.y, pa.z, pa.w};
    u16x4 hv, lv;
#pragma unroll
    for (int j = 0; j < 4; ++j) {
      unsigned short hb = f2bf(vv[j]);
      hv[j] = hb;
      lv[j] = f2bf(vv[j] - bf2f(hb));
    }
    u16* base = sAB + pb*BUFU;
    const int aoff = (ar >> 4)*512 + ((ar & 15) + ((ak >> 3) << 4))*8 + (ak & 7);
    *(u16x4*)(base + aoff) = hv;
    *(u16x4*)(base + 2048 + aoff) = lv;
    float* wb = (float*)(base + 4096) + tid*8;
    *(float4*)wb = w0; *(float4*)(wb + 4) = w1;
  };
  auto compute = [&](int pb) {
    u16* base = sAB + pb*BUFU;
    const u16* Ap = base + wr*512 + lane*8;
    bf16x8 a_hi = *(const bf16x8*)Ap;
    bf16x8 a_lo = *(const bf16x8*)(Ap + 2048);
    const u16* Bp = base + 4096 + (wc*4)*1024 + lane*8;
#pragma unroll
    for (int t = 0; t < 4; ++t) {
      bf16x8 b_hi = *(const bf16x8*)(Bp + t*1024);
      bf16x8 b_lo = *(const bf16x8*)(Bp + t*1024 + 512);
      acc[t] = __builtin_amdgcn_mfma_f32_16x16x32_bf16(a_hi, b_hi, acc[t], 0, 0, 0);
      acc[t] = __builtin_amdgcn_mfma_f32_16x16x32_bf16(a_lo, b_hi, acc[t], 0, 0, 0);
      acc[t] = __builtin_amdgcn_mfma_f32_16x16x32_bf16(a_hi, b_lo, acc[t], 0, 0, 0);
    }
  };

  float4 pa0, pa1, pw00, pw01, pw10, pw11;
  pa0 = lda(0); ldw(0, pw00, pw01);
  pa1 = lda(1); ldw(1, pw10, pw11);
  storec(0, pa0, pw00, pw01);
  __syncthreads();
  for (int c = 0; c < NCH; c += 2) {
    if (c + 2 < NCH) { pa0 = lda(c+2); ldw(c+2, pw00, pw01); }
    compute(0);
    storec(1, pa1, pw10, pw11);
    __syncthreads();
    if (c + 3 < NCH) { pa1 = lda(c+3); ldw(c+3, pw10, pw11); }
    compute(1);
    if (c + 2 < NCH) storec(0, pa0, pw00, pw01);
    __syncthreads();
  }

  if (HASE) {
#pragma unroll
    for (int t = 0; t < 4; ++t) {
      const int colL = wc*64 + t*16 + (lane & 15);
      float w[8];
#pragma unroll
      for (int j = 0; j < 8; ++j) w[j] = sWe[j*128 + colL];
#pragma unroll
      for (int m = 0; m < 4; ++m) {
        const int rr = wr*16 + ((lane >> 4) << 2) + m;
        float s = 0.f;
#pragma unroll
        for (int j = 0; j < 8; ++j) s = __builtin_fmaf(sE[rr*8 + j], w[j], s);
        acc[t][m] += s;
      }
    }
  }
  fe(wr, wc, lane, acc);
}

// ---------------- MFMA epilogues ----------------
struct GateEpiM {
  const float* cin; float* ho; float* co; const float* bias_pk;
  int r0; int ct0; int hb0;
  __device__ void operator()(int wr, int wc, int lane, f32x4 (&acc)[4]) const {
    const int h = hb0 + wc*16 + (lane & 15);
    const int rbase = r0 + wr*16 + ((lane >> 4) << 2);
    float b[4];
#pragma unroll
    for (int t = 0; t < 4; ++t) b[t] = bias_pk[ct0 + wc*64 + t*16 + (lane & 15)];
#pragma unroll
    for (int m = 0; m < 4; ++m) {
      const size_t ix = (size_t)(rbase + m)*H_ + h;
      float gi = sig_(acc[0][m] + b[0]);
      float gf = sig_(acc[1][m] + b[1]);
      float gg = tanh_(acc[2][m] + b[2]);
      float go = sig_(acc[3][m] + b[3]);
      float cn = gf*cin[ix] + gi*gg;
      ho[ix] = go*tanh_(cn); co[ix] = cn;
    }
  }
};

struct MlpEpiM {
  float* dst; int r0; int ct0;
  __device__ void operator()(int wr, int wc, int lane, f32x4 (&acc)[4]) const {
    const int rbase = r0 + wr*16 + ((lane >> 4) << 2);
    const int c0 = ct0 + wc*64 + (lane & 15);
#pragma unroll
    for (int t = 0; t < 4; ++t)
#pragma unroll
      for (int m = 0; m < 4; ++m)
        dst[(size_t)(rbase + m)*512 + c0 + t*16] = acc[t][m];
  }
};

// ---- fused p-MLP2 + head + softmax + mix (reads K-split partials) ----
__device__ __forceinline__ void stage_F2(
    int rowbase,
    const float* mlpA, const float* mlpB, const float* b1,
    const float* WB, const float* b2,
    const float* W3, const float* b3,
    const float* lh, const float* lc,
    const float* ghp, const float* gcp,
    float* ghc, float* gcc)
{
  const int w = threadIdx.x >> 6, lane = threadIdx.x & 63;
  const int r0 = rowbase + w*2;
  const float* aA0 = mlpA + (size_t)r0*512; const float* aB0 = mlpB + (size_t)r0*512;
  const float* aA1 = aA0 + 512;             const float* aB1 = aB0 + 512;
  float m0[4] = {0.f,0.f,0.f,0.f}, m1[4] = {0.f,0.f,0.f,0.f};
  for (int k0 = 0; k0 < 512; k0 += 4) {
    float4 xa = *(const float4*)&aA0[k0];
    float4 xb = *(const float4*)&aB0[k0];
    float4 ya = *(const float4*)&aA1[k0];
    float4 yb = *(const float4*)&aB1[k0];
    float4 bb = *(const float4*)&b1[k0];
    float xv0[4] = { fmaxf(xa.x+xb.x+bb.x,0.f), fmaxf(xa.y+xb.y+bb.y,0.f),
                     fmaxf(xa.z+xb.z+bb.z,0.f), fmaxf(xa.w+xb.w+bb.w,0.f) };
    float xv1[4] = { fmaxf(ya.x+yb.x+bb.x,0.f), fmaxf(ya.y+yb.y+bb.y,0.f),
                     fmaxf(ya.z+yb.z+bb.z,0.f), fmaxf(ya.w+yb.w+bb.w,0.f) };
#pragma unroll
    for (int j = 0; j < 4; ++j) {
      float4 wv = *(const float4*)&WB[(size_t)(k0+j)*256 + lane*4];
      m0[0] = __builtin_fmaf(xv0[j], wv.x, m0[0]);
      m0[1] = __builtin_fmaf(xv0[j], wv.y, m0[1]);
      m0[2] = __builtin_fmaf(xv0[j], wv.z, m0[2]);
      m0[3] = __builtin_fmaf(xv0[j], wv.w, m0[3]);
      m1[0] = __builtin_fmaf(xv1[j], wv.x, m1[0]);
      m1[1] = __builtin_fmaf(xv1[j], wv.y, m1[1]);
      m1[2] = __builtin_fmaf(xv1[j], wv.z, m1[2]);
      m1[3] = __builtin_fmaf(xv1[j], wv.w, m1[3]);
    }
  }
  float4 b = *(const float4*)&b2[lane*4];
  float bb2[4] = {b.x,b.y,b.z,b.w};
#pragma unroll
  for (int j = 0; j < 4; ++j) {
    m0[j] = fmaxf(m0[j]+bb2[j], 0.f);
    m1[j] = fmaxf(m1[j]+bb2[j], 0.f);
  }
  float4 w30 = *(const float4*)&W3[lane*4];
  float4 w31 = *(const float4*)&W3[256 + lane*4];
  float w0v[4] = {w30.x,w30.y,w30.z,w30.w};
  float w1v[4] = {w31.x,w31.y,w31.z,w31.w};
  float d00=0.f, d01=0.f, d10=0.f, d11=0.f;
#pragma unroll
  for (int j = 0; j < 4; ++j) {
    d00 = __builtin_fmaf(m0[j], w0v[j], d00);
    d01 = __builtin_fmaf(m0[j], w1v[j], d01);
    d10 = __builtin_fmaf(m1[j], w0v[j], d10);
    d11 = __builtin_fmaf(m1[j], w1v[j], d11);
  }
#pragma unroll
  for (int off = 32; off; off >>= 1) {
    d00 += __shfl_xor(d00, off, 64); d01 += __shfl_xor(d01, off, 64);
    d10 += __shfl_xor(d10, off, 64); d11 += __shfl_xor(d11, off, 64);
  }
  d00 += b3[0]; d01 += b3[1]; d10 += b3[0]; d11 += b3[1];
  float mxa = fmaxf(d00, d01), mxb = fmaxf(d10, d11);
  float e00 = __expf(d00-mxa), e01 = __expf(d01-mxa);
  float e10 = __expf(d10-mxb), e11 = __expf(d11-mxb);
  float ia = 1.f/(e00+e01), ib = 1.f/(e10+e11);
  float p0a = e00*ia, p1a = e01*ia;
  float p0b = e10*ib, p1b = e11*ib;
#pragma unroll
  for (int rr = 0; rr < 2; ++rr) {
    const float p0 = rr ? p0b : p0a, p1 = rr ? p1b : p1a;
    const size_t ix = (size_t)(r0+rr)*H_ + lane*4;
    float4 lv = *(const float4*)&lh[ix];
    float4 gv = *(const float4*)&ghp[ix];
    float4 o;
    o.x = p0*lv.x + p1*gv.x; o.y = p0*lv.y + p1*gv.y;
    o.z = p0*lv.z + p1*gv.z; o.w = p0*lv.w + p1*gv.w;
    *(float4*)&ghc[ix] = o;
    lv = *(const float4*)&lc[ix];
    gv = *(const float4*)&gcp[ix];
    o.x = p0*lv.x + p1*gv.x; o.y = p0*lv.y + p1*gv.y;
    o.z = p0*lv.z + p1*gv.z; o.w = p0*lv.w + p1*gv.w;
    *(float4*)&gcc[ix] = o;
  }
}

// -------- output projection, 8 rows per block (wave per row) --------
__device__ __forceinline__ void stage_OUT(
    const float* gh2c, const float* WOUT, const float* BOUT,
    float* out, int rbase, int tt)
{
  const int w = threadIdx.x >> 6, lane = threadIdx.x & 63;
  const int r = rbase + w;
  const float* arow = gh2c + (size_t)r * H_;
  float acc0 = 0.f, acc1 = 0.f;
  const bool two = lane < (V_ - 64);
  for (int k0 = 0; k0 < 256; k0 += 4) {
    float4 a4 = *(const float4*)&arow[k0];
    float av[4] = {a4.x, a4.y, a4.z, a4.w};
#pragma unroll
    for (int j = 0; j < 4; ++j) {
      const float* wr_ = &WOUT[(size_t)(k0+j)*96];
      acc0 = __builtin_fmaf(av[j], wr_[lane], acc0);
      if (two) acc1 = __builtin_fmaf(av[j], wr_[64+lane], acc1);
    }
  }
  out[((size_t)r*V_ + lane)*T_ + tt] = acc0 + BOUT[lane];
  if (two) out[((size_t)r*V_ + 64 + lane)*T_ + tt] = acc1 + BOUT[64+lane];
}

// ---------------- setup: zero states/bar, gather ex0, pack weights ---------
__global__ void k_setup(InP in, float* __restrict__ ws)
{
  const size_t nthr = (size_t)gridDim.x * blockDim.x;
  const size_t t0 = (size_t)blockIdx.x * blockDim.x + threadIdx.x;

  for (size_t i = t0; i < 16*(size_t)S_; i += nthr) ws[i] = 0.f;
  for (size_t i = t0; i < 8192; i += nthr) ((unsigned*)(ws + OFF_BAR))[i] = 0u;

  for (size_t i = t0; i < (size_t)B_*8; i += nthr) {
    int r = (int)(i >> 3), j = (int)(i & 7);
    ws[OFF_EX + i] = in.emb[(size_t)in.seq[(size_t)r*T_]*8 + j];
  }

  // ---- WG1pk: K=256, N=2048 (Whh of g1|l1, gate-grouped cols) ----
  {
    u16* dst = (u16*)(ws + OFF_WG1PK);
    for (size_t i = t0; i < (size_t)8*128*512; i += nthr) {
      int e = (int)(i & 7), lane = (int)((i >> 3) & 63);
      int tile = (int)((i >> 9) & 127), ck = (int)(i >> 16);
      int p = tile*16 + (lane & 15);
      int k = ck*32 + ((lane >> 4) << 3) + e;
      int cell = p >> 10, q = p & 1023;
      int h = ((q >> 6) << 4) + (q & 15), g = (q >> 4) & 3, R = g*256 + h;
      float w = (cell ? in.l1_Whh : in.g1_Whh)[(size_t)R*256 + k];
      unsigned short hb = f2bf(w), lb = f2bf(w - bf2f(hb));
      size_t o = ((size_t)(ck*128 + tile)*2)*512 + lane*8 + e;
      dst[o] = hb; dst[o + 512] = lb;
    }
  }
  // WE1 fp32 [8][2048 packed] and BG1 packed
  for (size_t i = t0; i < (size_t)8*2048; i += nthr) {
    int j = (int)(i >> 11), p = (int)(i & 2047);
    int cell = p >> 10, q = p & 1023;
    int h = ((q >> 6) << 4) + (q & 15), g = (q >> 4) & 3, R = g*256 + h;
    ws[OFF_WE1_ + (size_t)j*2048 + p] = (cell ? in.l1_Wih : in.g1_Wih)[(size_t)R*8 + j];
  }
  for (size_t i = t0; i < 2048; i += nthr) {
    int p = (int)i, cell = p >> 10, q = p & 1023;
    int h = ((q >> 6) << 4) + (q & 15), g = (q >> 4) & 3, R = g*256 + h;
    ws[OFF_BG1 + i] = cell ? (in.l1_bih[R] + in.l1_bhh[R]) : (in.g1_bih[R] + in.g1_bhh[R]);
  }

  // ---- WL2pk / WG2pk: K=512, N=1024 ----
  for (int which = 0; which < 2; ++which) {
    u16* dst = (u16*)(ws + (which ? OFF_WG2PK : OFF_WL2PK));
    const float* Wih = which ? in.g2_Wih : in.l2_Wih;
    const float* Whh = which ? in.g2_Whh : in.l2_Whh;
    for (size_t i = t0; i < (size_t)16*64*512; i += nthr) {
      int e = (int)(i & 7), lane = (int)((i >> 3) & 63);
      int tile = (int)((i >> 9) & 63), ck = (int)(i >> 15);
      int p = tile*16 + (lane & 15);
      int k = ck*32 + ((lane >> 4) << 3) + e;
      int h = ((p >> 6) << 4) + (p & 15), g = (p >> 4) & 3, R = g*256 + h;
      float w = (k < 256) ? Wih[(size_t)R*256 + k] : Whh[(size_t)R*256 + (k-256)];
      unsigned short hb = f2bf(w), lb = f2bf(w - bf2f(hb));
      size_t o = ((size_t)(ck*64 + tile)*2)*512 + lane*8 + e;
      dst[o] = hb; dst[o + 512] = lb;
    }
  }
  for (size_t i = t0; i < 2*1024; i += nthr) {
    int which = (int)(i >> 10), p = (int)(i & 1023);
    int h = ((p >> 6) << 4) + (p & 15), g = (p >> 4) & 3, R = g*256 + h;
    float v = which ? (in.g2_bih[R] + in.g2_bhh[R]) : (in.l2_bih[R] + in.l2_bhh[R]);
    ws[(which ? OFF_BG2 : OFF_BL2) + p] = v;
  }

  // ---- WP1pk / WP2pk: K=1024, N=512 (cols natural) ----
  for (int which = 0; which < 2; ++which) {
    u16* dst = (u16*)(ws + (which ? OFF_WP2PK : OFF_WP1PK));
    const float* W = which ? in.p2_W1 : in.p1_W1;
    for (size_t i = t0; i < (size_t)32*32*512; i += nthr) {
      int e = (int)(i & 7), lane = (int)((i >> 3) & 63);
      int tile = (int)((i >> 9) & 31), ck = (int)(i >> 14);
      int p = tile*16 + (lane & 15);
      int k = ck*32 + ((lane >> 4) << 3) + e;
      float w = W[(size_t)p*1032 + 8 + k];
      unsigned short hb = f2bf(w), lb = f2bf(w - bf2f(hb));
      size_t o = ((size_t)(ck*32 + tile)*2)*512 + lane*8 + e;
      dst[o] = hb; dst[o + 512] = lb;
    }
  }
  for (size_t i = t0; i < (size_t)2*8*512; i += nthr) {
    int which = (int)(i / (8*512));
    int idx = (int)(i - (size_t)which*8*512);
    int j = idx >> 9, p = idx & 511;
    const float* W = which ? in.p2_W1 : in.p1_W1;
    ws[(which ? OFF_WEP2 : OFF_WEP1) + (size_t)j*512 + p] = W[(size_t)p*1032 + j];
  }

  // WB (fp32 k-major), WOUT, BOUT
  for (size_t i = t0; i < (size_t)2*512*256; i += nthr) {
    int which = (int)(i / (512*256));
    int idx = (int)(i - (size_t)which*512*256);
    int k = idx >> 8, n = idx & 255;
    const float* W = which ? in.p2_W2 : in.p1_W2;
    ws[(which ? OFF_WB2 : OFF_WB1) + idx] = W[(size_t)n*512 + k];
  }
  for (size_t i = t0; i < (size_t)256*96; i += nthr) {
    int k = (int)(i / 96), c = (int)(i - (size_t)k*96);
    float v = 0.f;
    if (c < V_) v = 0.5f*(in.gfc_W[(size_t)c*256 + k] + in.lfc_W[(size_t)c*256 + k]);
    ws[OFF_WOUT + i] = v;
  }
  for (size_t i = t0; i < 96; i += nthr)
    ws[OFF_BOUT + i] = (i < V_) ? 0.5f*(in.gfc_b[i] + in.lfc_b[i]) : 0.f;
}

// ---------------- main persistent kernel (XCD-local, MFMA GEMMs) ----------------
__global__ __launch_bounds__(NTHR) void k_main(InP in, float* ws, float* __restrict__ out)
{
  __shared__ __attribute__((aligned(16))) u16   sAB[2*12288];  // 48KB
  __shared__ __attribute__((aligned(16))) float sWe[8*128];    // 4KB
  __shared__ __attribute__((aligned(16))) float sE[512];       // 2KB
  // + 28KB dynamic LDS -> >80KB total -> 1 block/CU, 32 blocks/XCD

  float* GH1C = ws + OFF_GH1C;  float* GC1C = ws + OFF_GC1C;
  float* GH1P = ws + OFF_GH1P;  float* GC1P = ws + OFF_GC1P;
  float* LH1  = ws + OFF_LH1;   float* LC1  = ws + OFF_LC1;
  float* GH2C = ws + OFF_GH2C;  float* GC2C = ws + OFF_GC2C;
  float* GH2P = ws + OFF_GH2P;  float* GC2P = ws + OFF_GC2P;
  float* LH2  = ws + OFF_LH2;   float* LC2  = ws + OFF_LC2;
  float* MLPA = ws + OFF_MLP1A; float* MLPB = ws + OFF_MLP1B;
  float* EXB  = ws + OFF_EX;
  const u16* WG1PK = (const u16*)(ws + OFF_WG1PK);
  const u16* WL2PK = (const u16*)(ws + OFF_WL2PK);
  const u16* WG2PK = (const u16*)(ws + OFF_WG2PK);
  const u16* WP1PK = (const u16*)(ws + OFF_WP1PK);
  const u16* WP2PK = (const u16*)(ws + OFF_WP2PK);
  const float* WE1 = ws + OFF_WE1_;  const float* BG1P = ws + OFF_BG1;
  const float* BL2P = ws + OFF_BL2;  const float* BG2P = ws + OFF_BG2;
  const float* WEP1 = ws + OFF_WEP1; const float* WEP2 = ws + OFF_WEP2;
  const float* WB1 = ws + OFF_WB1;   const float* WB2 = ws + OFF_WB2;
  const float* WOUT = ws + OFF_WOUT; const float* BOUT = ws + OFF_BOUT;

  unsigned xcc;
  asm volatile("s_getreg_b32 %0, hwreg(HW_REG_XCC_ID)" : "=s"(xcc));
  xcc &= 7u;
  unsigned* barx = ((unsigned*)(ws + OFF_BAR)) + xcc*1024;
  unsigned* arr  = barx;
  unsigned* go   = barx + 512;
  unsigned* reg  = barx + 544;
  __shared__ unsigned s_slot;
  if (threadIdx.x == 0)
    s_slot = __hip_atomic_fetch_add(reg, 1u, __ATOMIC_RELAXED, __HIP_MEMORY_SCOPE_AGENT);
  __syncthreads();
  const int slot  = (int)(s_slot & 31u);
  const int rows0 = (int)xcc * 128;
  unsigned ep = 0;

  for (int t = 0; t < T_; ++t) {
    const int sel = t & 1;
    const float* ex = EXB + sel*(B_*8);
    float* lh1o = LH1 + sel*S_;      float* lh1n = LH1 + (sel^1)*S_;
    float* lc1o = LC1 + sel*S_;      float* lc1n = LC1 + (sel^1)*S_;
    float* lh2o = LH2 + sel*S_;      float* lh2n = LH2 + (sel^1)*S_;
    float* lc2o = LC2 + sel*S_;      float* lc2n = LC2 + (sel^1)*S_;

    // ===== S1: layer-1 gates (g1 cols 0-1023 | l1 cols 1024-2047), 32 slots =====
    {
      const int rt = slot & 1, ct = slot >> 1;      // ct 0..15
      const int r0 = rows0 + rt*64, ct0 = ct*128;
      const int cell = ct >> 3;
      GateEpiM epi{ cell ? lc1o : GC1C,
                    cell ? lh1n : GH1P,
                    cell ? lc1n : GC1P,
                    BG1P, r0, ct0, ((ct0 & 1023) >> 6) << 4 };
      mm_mfma<8, 1, true>(sAB, sWe, sE,
                          cell ? lh1o : GH1C, nullptr,
                          WG1PK + (size_t)(ct0 >> 4)*1024, 128*1024,
                          WE1, 2048, ex, r0, ct0, epi);
    }
    gbar_x(arr, go, slot, ++ep);

    // ===== S2: p1-MLP1 K-split (slots 0-15) || l2 gates (slots 16-31) =====
    if (slot < 16) {
      const int rt = slot & 1, q = slot >> 1;       // q 0..7
      const int ct = q & 3, kh = q >> 2;
      const int r0 = rows0 + rt*64, ct0 = ct*128;
      if (kh == 0) {
        MlpEpiM epi{ MLPA, r0, ct0 };
        mm_mfma<16, 2, false>(sAB, sWe, sE, GH1P, GC1P,
                              WP1PK + (size_t)(ct0 >> 4)*1024, 32*1024,
                              nullptr, 0, nullptr, r0, ct0, epi);
      } else {
        MlpEpiM epi{ MLPB, r0, ct0 };
        mm_mfma<16, 2, true>(sAB, sWe, sE, lh1n, lc1n,
                             WP1PK + (size_t)16*32*1024 + (size_t)(ct0 >> 4)*1024, 32*1024,
                             WEP1, 512, ex, r0, ct0, epi);
      }
    } else {
      const int s2 = slot - 16;
      const int rt = s2 & 1, ct = s2 >> 1;          // ct 0..7
      const int r0 = rows0 + rt*64, ct0 = ct*128;
      GateEpiM epi{ lc2o, lh2n, lc2n, BL2P, r0, ct0, (ct0 >> 6) << 4 };
      mm_mfma<16, 2, false>(sAB, sWe, sE, lh1n, lh2o,
                            WL2PK + (size_t)(ct0 >> 4)*1024, 64*1024,
                            nullptr, 0, nullptr, r0, ct0, epi);
    }
    gbar_x(arr, go, slot, ++ep);

    // ===== S3: p1 finish + mix1 (slots 0-7) || ex(t+1) (slots 8-9) =====
    if (slot < 8) {
      stage_F2(rows0 + slot*16, MLPA, MLPB, in.p1_b1, WB1, in.p1_b2,
               in.p1_W3, in.p1_b3, lh1n, lc1n, GH1P, GC1P, GH1C, GC1C);
    } else if (slot < 10 && t < T_-1) {
      const int rb = rows0 + (slot-8)*64;
      const int r = rb + (threadIdx.x >> 3), j = threadIdx.x & 7;
      EXB[((t+1)&1)*(B_*8) + r*8 + j] = in.emb[(size_t)in.seq[(size_t)r*T_ + t + 1]*8 + j];
    }
    gbar_x(arr, go, slot, ++ep);

    // ===== S4: g2 gates (slots 0-15) || out(t-1) (slots 16-31) =====
    if (slot < 16) {
      const int rt = slot & 1, ct = slot >> 1;      // ct 0..7
      const int r0 = rows0 + rt*64, ct0 = ct*128;
      GateEpiM epi{ GC2C, GH2P, GC2P, BG2P, r0, ct0, (ct0 >> 6) << 4 };
      mm_mfma<16, 2, false>(sAB, sWe, sE, GH1C, GH2C,
                            WG2PK + (size_t)(ct0 >> 4)*1024, 64*1024,
                            nullptr, 0, nullptr, r0, ct0, epi);
    } else if (t > 0) {
      stage_OUT(GH2C, WOUT, BOUT, out, rows0 + (slot-16)*8, t-1);
    }
    gbar_x(arr, go, slot, ++ep);

    // ===== S5: p2-MLP1 K-split (slots 0-15) =====
    if (slot < 16) {
      const int rt = slot & 1, q = slot >> 1;
      const int ct = q & 3, kh = q >> 2;
      const int r0 = rows0 + rt*64, ct0 = ct*128;
      if (kh == 0) {
        MlpEpiM epi{ MLPA, r0, ct0 };
        mm_mfma<16, 2, false>(sAB, sWe, sE, GH2P, GC2P,
                              WP2PK + (size_t)(ct0 >> 4)*1024, 32*1024,
                              nullptr, 0, nullptr, r0, ct0, epi);
      } else {
        MlpEpiM epi{ MLPB, r0, ct0 };
        mm_mfma<16, 2, true>(sAB, sWe, sE, lh2n, lc2n,
                             WP2PK + (size_t)16*32*1024 + (size_t)(ct0 >> 4)*1024, 32*1024,
                             WEP2, 512, ex, r0, ct0, epi);
      }
    }
    gbar_x(arr, go, slot, ++ep);

    // ===== S6: p2 finish + mix2 (slots 0-7) =====
    if (slot < 8) {
      stage_F2(rows0 + slot*16, MLPA, MLPB, in.p2_b1, WB2, in.p2_b2,
               in.p2_W3, in.p2_b3, lh2n, lc2n, GH2P, GC2P, GH2C, GC2C);
    }
    gbar_x(arr, go, slot, ++ep);
  }

  // final output column t = 255
  if (slot >= 16) stage_OUT(GH2C, WOUT, BOUT, out, rows0 + (slot-16)*8, 255);
}

// ---------------- host ----------------
extern "C" void kernel_launch(void* const* d_in, const int* in_sizes, int n_in,
                              void* d_out, int out_size, void* d_ws, size_t ws_size,
                              hipStream_t stream)
{
  if (ws_size < WS_FLOATS * sizeof(float)) return;

  InP in;
  in.seq    = (const int*)  d_in[0];
  in.emb    = (const float*)d_in[1];
  in.g1_Wih = (const float*)d_in[2];  in.g1_Whh = (const float*)d_in[3];
  in.g1_bih = (const float*)d_in[4];  in.g1_bhh = (const float*)d_in[5];
  in.g2_Wih = (const float*)d_in[6];  in.g2_Whh = (const float*)d_in[7];
  in.g2_bih = (const float*)d_in[8];  in.g2_bhh = (const float*)d_in[9];
  in.l1_Wih = (const float*)d_in[10]; in.l1_Whh = (const float*)d_in[11];
  in.l1_bih = (const float*)d_in[12]; in.l1_bhh = (const float*)d_in[13];
  in.l2_Wih = (const float*)d_in[14]; in.l2_Whh = (const float*)d_in[15];
  in.l2_bih = (const float*)d_in[16]; in.l2_bhh = (const float*)d_in[17];
  in.p1_W1  = (const float*)d_in[18]; in.p1_b1  = (const float*)d_in[19];
  in.p1_W2  = (const float*)d_in[20]; in.p1_b2  = (const float*)d_in[21];
  in.p1_W3  = (const float*)d_in[22]; in.p1_b3  = (const float*)d_in[23];
  in.p2_W1  = (const float*)d_in[24]; in.p2_b1  = (const float*)d_in[25];
  in.p2_W2  = (const float*)d_in[26]; in.p2_b2  = (const float*)d_in[27];
  in.p2_W3  = (const float*)d_in[28]; in.p2_b3  = (const float*)d_in[29];
  in.gfc_W  = (const float*)d_in[30]; in.gfc_b  = (const float*)d_in[31];
  in.lfc_W  = (const float*)d_in[32]; in.lfc_b  = (const float*)d_in[33];

  float* ws  = (float*)d_ws;
  float* out = (float*)d_out;

  k_setup<<<512, 256, 0, stream>>>(in, ws);
  k_main <<<NBLK, NTHR, 28672, stream>>>(in, ws, out);   // dynamic LDS: occupancy pin
}

// Round 9
// 63862.305 us; speedup vs baseline: 1.2737x; 1.2737x over previous
//
#include <hip/hip_runtime.h>

#define B_ 1024
#define T_ 256
#define V_ 90
#define H_ 256
#define NTHR 512
#define NBLK 256
#define S_ ((size_t)B_*H_)

typedef unsigned short u16;
typedef __attribute__((ext_vector_type(8))) _Float16 f16x8;
typedef __attribute__((ext_vector_type(4))) _Float16 f16x4;
typedef __attribute__((ext_vector_type(4))) float f32x4;

// ---------------- ws layout (float offsets) ----------------
constexpr size_t OFF_GH1C  = 0;
constexpr size_t OFF_GC1C  = OFF_GH1C + S_;
constexpr size_t OFF_GH1P  = OFF_GC1C + S_;
constexpr size_t OFF_GC1P  = OFF_GH1P + S_;
constexpr size_t OFF_LH1   = OFF_GC1P + S_;      // 2 buffers
constexpr size_t OFF_LC1   = OFF_LH1 + 2*S_;
constexpr size_t OFF_GH2C  = OFF_LC1 + 2*S_;
constexpr size_t OFF_GC2C  = OFF_GH2C + S_;
constexpr size_t OFF_GH2P  = OFF_GC2C + S_;
constexpr size_t OFF_GC2P  = OFF_GH2P + S_;
constexpr size_t OFF_LH2   = OFF_GC2P + S_;      // 2 buffers
constexpr size_t OFF_LC2   = OFF_LH2 + 2*S_;
constexpr size_t OFF_M1A   = OFF_LC2 + 2*S_;     // p1 partials (K-split)
constexpr size_t OFF_M1B   = OFF_M1A + (size_t)B_*512;
constexpr size_t OFF_M2A   = OFF_M1B + (size_t)B_*512;  // p2 partials
constexpr size_t OFF_M2B   = OFF_M2A + (size_t)B_*512;
constexpr size_t OFF_EX    = OFF_M2B + (size_t)B_*512;  // 2*1024*8
// fp16 packed weights (u16 counts halved into float units)
constexpr size_t OFF_WG1PK = OFF_EX + 2*B_*8;            // 256x2048 fp16
constexpr size_t OFF_WE1   = OFF_WG1PK + 256*2048/2;     // fp32 [8][2048pk]
constexpr size_t OFF_BG1   = OFF_WE1 + 8*2048;
constexpr size_t OFF_WL2PK = OFF_BG1 + 2048;             // 512x1024 fp16
constexpr size_t OFF_BL2   = OFF_WL2PK + 512*1024/2;
constexpr size_t OFF_WG2PK = OFF_BL2 + 1024;
constexpr size_t OFF_BG2   = OFF_WG2PK + 512*1024/2;
constexpr size_t OFF_WP1PK = OFF_BG2 + 1024;             // 1024x512 fp16
constexpr size_t OFF_WEP1  = OFF_WP1PK + 1024*512/2;
constexpr size_t OFF_WP2PK = OFF_WEP1 + 8*512;
constexpr size_t OFF_WEP2  = OFF_WP2PK + 1024*512/2;
constexpr size_t OFF_WB1   = OFF_WEP2 + 8*512;           // fp32 [512][256]
constexpr size_t OFF_WB2   = OFF_WB1 + 512*256;
constexpr size_t OFF_WOUT  = OFF_WB2 + 512*256;          // fp32 [256][96]
constexpr size_t OFF_BOUT  = OFF_WOUT + 256*96;
constexpr size_t OFF_BAR   = OFF_BOUT + 128;             // 8 XCD * 1024 uints
constexpr size_t WS_FLOATS = OFF_BAR + 8192;

struct InP {
  const int*   seq;
  const float* emb;
  const float *g1_Wih,*g1_Whh,*g1_bih,*g1_bhh;
  const float *g2_Wih,*g2_Whh,*g2_bih,*g2_bhh;
  const float *l1_Wih,*l1_Whh,*l1_bih,*l1_bhh;
  const float *l2_Wih,*l2_Whh,*l2_bih,*l2_bhh;
  const float *p1_W1,*p1_b1,*p1_W2,*p1_b2,*p1_W3,*p1_b3;
  const float *p2_W1,*p2_b1,*p2_W2,*p2_b2,*p2_W3,*p2_b3;
  const float *gfc_W,*gfc_b,*lfc_W,*lfc_b;
};

__device__ __forceinline__ float sig_(float x)  { return 1.f/(1.f+__expf(-x)); }
__device__ __forceinline__ float tanh_(float x) { return 1.f - 2.f/(__expf(2.f*x)+1.f); }
__device__ __forceinline__ u16 f2h(float v) {
  _Float16 h = (_Float16)v; return __builtin_bit_cast(unsigned short, h);
}

// ---- AGENT-scope (sc1) flag ops (R7-proven) ----
__device__ __forceinline__ unsigned ld_flag(const unsigned* p) {
  unsigned v;
  asm volatile("global_load_dword %0, %1, off sc1\n\ts_waitcnt vmcnt(0)"
               : "=v"(v) : "v"(p) : "memory");
  return v;
}
__device__ __forceinline__ void st_flag(unsigned* p, unsigned v) {
  asm volatile("global_store_dword %0, %1, off sc1\n\ts_waitcnt vmcnt(0)"
               :: "v"(p), "v"(v) : "memory");
}

// -------- per-XCD barrier: all-poll epoch flags, no leader hop --------
// Each block stores its epoch to its own 64B-strided word; 32 lanes of wave0
// poll all 32 words directly (one vector load per iteration). Removes the
// leader-aggregate + go-broadcast serial hops of R7's barrier.
__device__ __forceinline__ void gbar_x(unsigned* arr, int slot, unsigned ep)
{
  __syncthreads();                       // drains vmcnt(0): stores in L2
  if (threadIdx.x == 0) st_flag(&arr[slot*16], ep);
  if (threadIdx.x < 32) {
    int cap = 0;
    for (;;) {
      unsigned v = ld_flag(&arr[threadIdx.x*16]);
      if (v >= ep) break;
      __builtin_amdgcn_s_sleep(1);
      if (++cap > 200000) break;
    }
  }
  __syncthreads();
  asm volatile("buffer_inv sc0" ::: "memory");   // vL1 invalidate only
}

// ============ fp16 MFMA tile GEMM: 64 rows x 128 cols, 8 waves ============
// Frag: A lane&15=row, B lane&15=col, same k-bijection k=(l>>4)*8+e both sides.
// C/D: col=l&15, row=(l>>4)*4+reg  [HW-verified, R8 passed]
// LDS buffer (u16): A 4 tiles x 512 | B 8 tiles x 512  => 6144 u16 = 12KB
template<int NCH, int NSEG, bool HASE, class FE>
__device__ __forceinline__ void mm_h(
    u16* sAB, float* sWe, float* sE,
    const float* s0, const float* s1_,
    const u16* Wpk, int wstep,
    const float* WeP, int ldwe, const float* ex,
    int r0, int ct0, FE fe)
{
  constexpr int BUFU = 6144;
  const int tid = threadIdx.x;
  const int lane = tid & 63;
  const int wr = (tid >> 6) & 3, wc = tid >> 8;
  const int ar = tid >> 3, ak = (tid & 7) << 2;

  __syncthreads();          // protect sWe/sAB reuse across back-to-back calls

  if (HASE) {
    for (int i = tid; i < 8*128; i += NTHR)
      sWe[i] = WeP[(i >> 7) * ldwe + ct0 + (i & 127)];
    sE[tid] = ex[((r0 + ar) << 3) + (tid & 7)];
  }

  f32x4 acc[4] = {{0,0,0,0},{0,0,0,0},{0,0,0,0},{0,0,0,0}};

  auto lda = [&](int c) -> float4 {
    int k0 = c * 32;
    const float* S = (NSEG == 1) ? s0 : ((k0 < 256) ? s0 : s1_);
    return *(const float4*)&S[(size_t)(r0 + ar) * H_ + (k0 & 255) + ak];
  };
  auto ldw = [&](int c) -> float4 {
    const float* p = (const float*)(Wpk + (size_t)c * wstep) + tid * 4;
    return *(const float4*)p;
  };
  auto storec = [&](int pb, const float4& pa, const float4& pw) {
    float vv[4] = {pa.x, pa.y, pa.z, pa.w};
    f16x4 hv;
#pragma unroll
    for (int j = 0; j < 4; ++j) hv[j] = (_Float16)vv[j];
    u16* base = sAB + pb*BUFU;
    const int aoff = (ar >> 4)*512 + ((ar & 15) + ((ak >> 3) << 4))*8 + (ak & 7);
    *(f16x4*)(base + aoff) = hv;
    *(float4*)((float*)(base + 2048) + tid*4) = pw;
  };
  auto compute = [&](int pb) {
    u16* base = sAB + pb*BUFU;
    f16x8 a = *(const f16x8*)(base + wr*512 + lane*8);
    const u16* Bp = base + 2048 + (wc*4)*512 + lane*8;
#pragma unroll
    for (int t = 0; t < 4; ++t) {
      f16x8 b = *(const f16x8*)(Bp + t*512);
      acc[t] = __builtin_amdgcn_mfma_f32_16x16x32_f16(a, b, acc[t], 0, 0, 0);
    }
  };

  float4 pa0, pa1, pw0, pw1;
  pa0 = lda(0); pw0 = ldw(0);
  pa1 = lda(1); pw1 = ldw(1);
  storec(0, pa0, pw0);
  __syncthreads();
  for (int c = 0; c < NCH; c += 2) {
    if (c + 2 < NCH) { pa0 = lda(c+2); pw0 = ldw(c+2); }
    compute(0);
    storec(1, pa1, pw1);
    __syncthreads();
    if (c + 3 < NCH) { pa1 = lda(c+3); pw1 = ldw(c+3); }
    compute(1);
    if (c + 2 < NCH) storec(0, pa0, pw0);
    __syncthreads();
  }

  if (HASE) {
#pragma unroll
    for (int t = 0; t < 4; ++t) {
      const int colL = wc*64 + t*16 + (lane & 15);
      float w[8];
#pragma unroll
      for (int j = 0; j < 8; ++j) w[j] = sWe[j*128 + colL];
#pragma unroll
      for (int m = 0; m < 4; ++m) {
        const int rr = wr*16 + ((lane >> 4) << 2) + m;
        float s = 0.f;
#pragma unroll
        for (int j = 0; j < 8; ++j) s = __builtin_fmaf(sE[rr*8 + j], w[j], s);
        acc[t][m] += s;
      }
    }
  }
  fe(wr, wc, lane, acc);
}

// ---------------- MFMA epilogues (R8-verified) ----------------
struct GateEpiM {
  const float* cin; float* ho; float* co; const float* bias_pk;
  int r0; int ct0; int hb0;
  __device__ void operator()(int wr, int wc, int lane, f32x4 (&acc)[4]) const {
    const int h = hb0 + wc*16 + (lane & 15);
    const int rbase = r0 + wr*16 + ((lane >> 4) << 2);
    float b[4];
#pragma unroll
    for (int t = 0; t < 4; ++t) b[t] = bias_pk[ct0 + wc*64 + t*16 + (lane & 15)];
#pragma unroll
    for (int m = 0; m < 4; ++m) {
      const size_t ix = (size_t)(rbase + m)*H_ + h;
      float gi = sig_(acc[0][m] + b[0]);
      float gf = sig_(acc[1][m] + b[1]);
      float gg = tanh_(acc[2][m] + b[2]);
      float go = sig_(acc[3][m] + b[3]);
      float cn = gf*cin[ix] + gi*gg;
      ho[ix] = go*tanh_(cn); co[ix] = cn;
    }
  }
};

struct MlpEpiM {
  float* dst; int r0; int ct0;
  __device__ void operator()(int wr, int wc, int lane, f32x4 (&acc)[4]) const {
    const int rbase = r0 + wr*16 + ((lane >> 4) << 2);
    const int c0 = ct0 + wc*64 + (lane & 15);
#pragma unroll
    for (int t = 0; t < 4; ++t)
#pragma unroll
      for (int m = 0; m < 4; ++m)
        dst[(size_t)(rbase + m)*512 + c0 + t*16] = acc[t][m];
  }
};

// ---- fused p-MLP2 + head + softmax + mix (K-split partials) ----
__device__ __forceinline__ void stage_F2(
    int rowbase,
    const float* mlpA, const float* mlpB, const float* b1,
    const float* WB, const float* b2,
    const float* W3, const float* b3,
    const float* lh, const float* lc,
    const float* ghp, const float* gcp,
    float* ghc, float* gcc)
{
  const int w = threadIdx.x >> 6, lane = threadIdx.x & 63;
  const int r0 = rowbase + w*2;
  const float* aA0 = mlpA + (size_t)r0*512; const float* aB0 = mlpB + (size_t)r0*512;
  const float* aA1 = aA0 + 512;             const float* aB1 = aB0 + 512;
  float m0[4] = {0.f,0.f,0.f,0.f}, m1[4] = {0.f,0.f,0.f,0.f};
  for (int k0 = 0; k0 < 512; k0 += 4) {
    float4 xa = *(const float4*)&aA0[k0];
    float4 xb = *(const float4*)&aB0[k0];
    float4 ya = *(const float4*)&aA1[k0];
    float4 yb = *(const float4*)&aB1[k0];
    float4 bb = *(const float4*)&b1[k0];
    float xv0[4] = { fmaxf(xa.x+xb.x+bb.x,0.f), fmaxf(xa.y+xb.y+bb.y,0.f),
                     fmaxf(xa.z+xb.z+bb.z,0.f), fmaxf(xa.w+xb.w+bb.w,0.f) };
    float xv1[4] = { fmaxf(ya.x+yb.x+bb.x,0.f), fmaxf(ya.y+yb.y+bb.y,0.f),
                     fmaxf(ya.z+yb.z+bb.z,0.f), fmaxf(ya.w+yb.w+bb.w,0.f) };
#pragma unroll
    for (int j = 0; j < 4; ++j) {
      float4 wv = *(const float4*)&WB[(size_t)(k0+j)*256 + lane*4];
      m0[0] = __builtin_fmaf(xv0[j], wv.x, m0[0]);
      m0[1] = __builtin_fmaf(xv0[j], wv.y, m0[1]);
      m0[2] = __builtin_fmaf(xv0[j], wv.z, m0[2]);
      m0[3] = __builtin_fmaf(xv0[j], wv.w, m0[3]);
      m1[0] = __builtin_fmaf(xv1[j], wv.x, m1[0]);
      m1[1] = __builtin_fmaf(xv1[j], wv.y, m1[1]);
      m1[2] = __builtin_fmaf(xv1[j], wv.z, m1[2]);
      m1[3] = __builtin_fmaf(xv1[j], wv.w, m1[3]);
    }
  }
  float4 b = *(const float4*)&b2[lane*4];
  float bb2[4] = {b.x,b.y,b.z,b.w};
#pragma unroll
  for (int j = 0; j < 4; ++j) {
    m0[j] = fmaxf(m0[j]+bb2[j], 0.f);
    m1[j] = fmaxf(m1[j]+bb2[j], 0.f);
  }
  float4 w30 = *(const float4*)&W3[lane*4];
  float4 w31 = *(const float4*)&W3[256 + lane*4];
  float w0v[4] = {w30.x,w30.y,w30.z,w30.w};
  float w1v[4] = {w31.x,w31.y,w31.z,w31.w};
  float d00=0.f, d01=0.f, d10=0.f, d11=0.f;
#pragma unroll
  for (int j = 0; j < 4; ++j) {
    d00 = __builtin_fmaf(m0[j], w0v[j], d00);
    d01 = __builtin_fmaf(m0[j], w1v[j], d01);
    d10 = __builtin_fmaf(m1[j], w0v[j], d10);
    d11 = __builtin_fmaf(m1[j], w1v[j], d11);
  }
#pragma unroll
  for (int off = 32; off; off >>= 1) {
    d00 += __shfl_xor(d00, off, 64); d01 += __shfl_xor(d01, off, 64);
    d10 += __shfl_xor(d10, off, 64); d11 += __shfl_xor(d11, off, 64);
  }
  d00 += b3[0]; d01 += b3[1]; d10 += b3[0]; d11 += b3[1];
  float mxa = fmaxf(d00, d01), mxb = fmaxf(d10, d11);
  float e00 = __expf(d00-mxa), e01 = __expf(d01-mxa);
  float e10 = __expf(d10-mxb), e11 = __expf(d11-mxb);
  float ia = 1.f/(e00+e01), ib = 1.f/(e10+e11);
  float p0a = e00*ia, p1a = e01*ia;
  float p0b = e10*ib, p1b = e11*ib;
#pragma unroll
  for (int rr = 0; rr < 2; ++rr) {
    const float p0 = rr ? p0b : p0a, p1 = rr ? p1b : p1a;
    const size_t ix = (size_t)(r0+rr)*H_ + lane*4;
    float4 lv = *(const float4*)&lh[ix];
    float4 gv = *(const float4*)&ghp[ix];
    float4 o;
    o.x = p0*lv.x + p1*gv.x; o.y = p0*lv.y + p1*gv.y;
    o.z = p0*lv.z + p1*gv.z; o.w = p0*lv.w + p1*gv.w;
    *(float4*)&ghc[ix] = o;
    lv = *(const float4*)&lc[ix];
    gv = *(const float4*)&gcp[ix];
    o.x = p0*lv.x + p1*gv.x; o.y = p0*lv.y + p1*gv.y;
    o.z = p0*lv.z + p1*gv.z; o.w = p0*lv.w + p1*gv.w;
    *(float4*)&gcc[ix] = o;
  }
}

// -------- output projection, 16 rows per block (2 rows/wave) --------
__device__ __forceinline__ void stage_OUT2(
    const float* gh2c, const float* WOUT, const float* BOUT,
    float* out, int rbase, int tt)
{
  const int w = threadIdx.x >> 6, lane = threadIdx.x & 63;
  const bool two = lane < (V_ - 64);
#pragma unroll
  for (int rr = 0; rr < 2; ++rr) {
    const int r = rbase + w*2 + rr;
    const float* arow = gh2c + (size_t)r * H_;
    float acc0 = 0.f, acc1 = 0.f;
    for (int k0 = 0; k0 < 256; k0 += 4) {
      float4 a4 = *(const float4*)&arow[k0];
      float av[4] = {a4.x, a4.y, a4.z, a4.w};
#pragma unroll
      for (int j = 0; j < 4; ++j) {
        const float* wr_ = &WOUT[(size_t)(k0+j)*96];
        acc0 = __builtin_fmaf(av[j], wr_[lane], acc0);
        if (two) acc1 = __builtin_fmaf(av[j], wr_[64+lane], acc1);
      }
    }
    out[((size_t)r*V_ + lane)*T_ + tt] = acc0 + BOUT[lane];
    if (two) out[((size_t)r*V_ + 64 + lane)*T_ + tt] = acc1 + BOUT[64+lane];
  }
}

// ---------------- setup: zero states/bar, gather ex0, pack fp16 weights ----
__global__ void k_setup(InP in, float* __restrict__ ws)
{
  const size_t nthr = (size_t)gridDim.x * blockDim.x;
  const size_t t0 = (size_t)blockIdx.x * blockDim.x + threadIdx.x;

  for (size_t i = t0; i < 16*S_; i += nthr) ws[i] = 0.f;
  for (size_t i = t0; i < 8192; i += nthr) ((unsigned*)(ws + OFF_BAR))[i] = 0u;

  for (size_t i = t0; i < (size_t)B_*8; i += nthr) {
    int r = (int)(i >> 3), j = (int)(i & 7);
    ws[OFF_EX + i] = in.emb[(size_t)in.seq[(size_t)r*T_]*8 + j];
  }

  // WG1pk: K=256, N=2048 (Whh of g1|l1, gate-grouped cols), fragment-major fp16
  {
    u16* dst = (u16*)(ws + OFF_WG1PK);
    for (size_t i = t0; i < (size_t)8*128*512; i += nthr) {
      int e = (int)(i & 7), lane = (int)((i >> 3) & 63);
      int tile = (int)((i >> 9) & 127), ck = (int)(i >> 16);
      int p = tile*16 + (lane & 15);
      int k = ck*32 + ((lane >> 4) << 3) + e;
      int cell = p >> 10, q = p & 1023;
      int h = ((q >> 6) << 4) + (q & 15), g = (q >> 4) & 3, R = g*256 + h;
      float w = (cell ? in.l1_Whh : in.g1_Whh)[(size_t)R*256 + k];
      dst[((size_t)(ck*128 + tile))*512 + lane*8 + e] = f2h(w);
    }
  }
  for (size_t i = t0; i < (size_t)8*2048; i += nthr) {
    int j = (int)(i >> 11), p = (int)(i & 2047);
    int cell = p >> 10, q = p & 1023;
    int h = ((q >> 6) << 4) + (q & 15), g = (q >> 4) & 3, R = g*256 + h;
    ws[OFF_WE1 + (size_t)j*2048 + p] = (cell ? in.l1_Wih : in.g1_Wih)[(size_t)R*8 + j];
  }
  for (size_t i = t0; i < 2048; i += nthr) {
    int p = (int)i, cell = p >> 10, q = p & 1023;
    int h = ((q >> 6) << 4) + (q & 15), g = (q >> 4) & 3, R = g*256 + h;
    ws[OFF_BG1 + i] = cell ? (in.l1_bih[R] + in.l1_bhh[R]) : (in.g1_bih[R] + in.g1_bhh[R]);
  }

  // WL2pk / WG2pk: K=512, N=1024
  for (int which = 0; which < 2; ++which) {
    u16* dst = (u16*)(ws + (which ? OFF_WG2PK : OFF_WL2PK));
    const float* Wih = which ? in.g2_Wih : in.l2_Wih;
    const float* Whh = which ? in.g2_Whh : in.l2_Whh;
    for (size_t i = t0; i < (size_t)16*64*512; i += nthr) {
      int e = (int)(i & 7), lane = (int)((i >> 3) & 63);
      int tile = (int)((i >> 9) & 63), ck = (int)(i >> 15);
      int p = tile*16 + (lane & 15);
      int k = ck*32 + ((lane >> 4) << 3) + e;
      int h = ((p >> 6) << 4) + (p & 15), g = (p >> 4) & 3, R = g*256 + h;
      float w = (k < 256) ? Wih[(size_t)R*256 + k] : Whh[(size_t)R*256 + (k-256)];
      dst[((size_t)(ck*64 + tile))*512 + lane*8 + e] = f2h(w);
    }
  }
  for (size_t i = t0; i < 2*1024; i += nthr) {
    int which = (int)(i >> 10), p = (int)(i & 1023);
    int h = ((p >> 6) << 4) + (p & 15), g = (p >> 4) & 3, R = g*256 + h;
    float v = which ? (in.g2_bih[R] + in.g2_bhh[R]) : (in.l2_bih[R] + in.l2_bhh[R]);
    ws[(which ? OFF_BG2 : OFF_BL2) + p] = v;
  }

  // WP1pk / WP2pk: K=1024, N=512 (natural cols)
  for (int which = 0; which < 2; ++which) {
    u16* dst = (u16*)(ws + (which ? OFF_WP2PK : OFF_WP1PK));
    const float* W = which ? in.p2_W1 : in.p1_W1;
    for (size_t i = t0; i < (size_t)32*32*512; i += nthr) {
      int e = (int)(i & 7), lane = (int)((i >> 3) & 63);
      int tile = (int)((i >> 9) & 31), ck = (int)(i >> 14);
      int p = tile*16 + (lane & 15);
      int k = ck*32 + ((lane >> 4) << 3) + e;
      dst[((size_t)(ck*32 + tile))*512 + lane*8 + e] = f2h(W[(size_t)p*1032 + 8 + k]);
    }
  }
  for (size_t i = t0; i < (size_t)2*8*512; i += nthr) {
    int which = (int)(i / (8*512));
    int idx = (int)(i - (size_t)which*8*512);
    int j = idx >> 9, p = idx & 511;
    const float* W = which ? in.p2_W1 : in.p1_W1;
    ws[(which ? OFF_WEP2 : OFF_WEP1) + (size_t)j*512 + p] = W[(size_t)p*1032 + j];
  }

  for (size_t i = t0; i < (size_t)2*512*256; i += nthr) {
    int which = (int)(i / (512*256));
    int idx = (int)(i - (size_t)which*512*256);
    int k = idx >> 8, n = idx & 255;
    const float* W = which ? in.p2_W2 : in.p1_W2;
    ws[(which ? OFF_WB2 : OFF_WB1) + idx] = W[(size_t)n*512 + k];
  }
  for (size_t i = t0; i < (size_t)256*96; i += nthr) {
    int k = (int)(i / 96), c = (int)(i - (size_t)k*96);
    float v = 0.f;
    if (c < V_) v = 0.5f*(in.gfc_W[(size_t)c*256 + k] + in.lfc_W[(size_t)c*256 + k]);
    ws[OFF_WOUT + i] = v;
  }
  for (size_t i = t0; i < 96; i += nthr)
    ws[OFF_BOUT + i] = (i < V_) ? 0.5f*(in.gfc_b[i] + in.lfc_b[i]) : 0.f;
}

// ------------- main persistent kernel: 3-phase software pipeline -------------
__global__ __launch_bounds__(NTHR) void k_main(InP in, float* ws, float* __restrict__ out)
{
  __shared__ __attribute__((aligned(16))) u16   sAB[2*6144];   // 24KB
  __shared__ __attribute__((aligned(16))) float sWe[8*128];    // 4KB
  __shared__ __attribute__((aligned(16))) float sE[512];       // 2KB
  // + 52KB dynamic LDS -> >80KB -> 1 block/CU, 32 blocks/XCD

  float* GH1C = ws + OFF_GH1C;  float* GC1C = ws + OFF_GC1C;
  float* GH1P = ws + OFF_GH1P;  float* GC1P = ws + OFF_GC1P;
  float* LH1  = ws + OFF_LH1;   float* LC1  = ws + OFF_LC1;
  float* GH2C = ws + OFF_GH2C;  float* GC2C = ws + OFF_GC2C;
  float* GH2P = ws + OFF_GH2P;  float* GC2P = ws + OFF_GC2P;
  float* LH2  = ws + OFF_LH2;   float* LC2  = ws + OFF_LC2;
  float* M1A  = ws + OFF_M1A;   float* M1B  = ws + OFF_M1B;
  float* M2A  = ws + OFF_M2A;   float* M2B  = ws + OFF_M2B;
  float* EXB  = ws + OFF_EX;
  const u16* WG1PK = (const u16*)(ws + OFF_WG1PK);
  const u16* WL2PK = (const u16*)(ws + OFF_WL2PK);
  const u16* WG2PK = (const u16*)(ws + OFF_WG2PK);
  const u16* WP1PK = (const u16*)(ws + OFF_WP1PK);
  const u16* WP2PK = (const u16*)(ws + OFF_WP2PK);
  const float* WE1  = ws + OFF_WE1;  const float* BG1P = ws + OFF_BG1;
  const float* BL2P = ws + OFF_BL2;  const float* BG2P = ws + OFF_BG2;
  const float* WEP1 = ws + OFF_WEP1; const float* WEP2 = ws + OFF_WEP2;
  const float* WB1  = ws + OFF_WB1;  const float* WB2  = ws + OFF_WB2;
  const float* WOUT = ws + OFF_WOUT; const float* BOUT = ws + OFF_BOUT;

  unsigned xcc;
  asm volatile("s_getreg_b32 %0, hwreg(HW_REG_XCC_ID)" : "=s"(xcc));
  xcc &= 7u;
  unsigned* barx = ((unsigned*)(ws + OFF_BAR)) + xcc*1024;
  unsigned* arr  = barx;
  unsigned* reg  = barx + 544;
  __shared__ unsigned s_slot;
  if (threadIdx.x == 0)
    s_slot = __hip_atomic_fetch_add(reg, 1u, __ATOMIC_RELAXED, __HIP_MEMORY_SCOPE_AGENT);
  __syncthreads();
  const int slot  = (int)(s_slot & 31u);
  const int rows0 = (int)xcc * 128;
  unsigned ep = 0;

  // cycle n: P_A gates1(n) || g2(n-1); P_B MLP1(n) || MLP2(n-1);
  //          P_C l2(n) || mix1(n)+ex(n+1) || mix2(n-1)+out(n-1)
  for (int n = 0; n <= T_; ++n) {
    const int sel = n & 1;
    const float* ex  = EXB + sel*(B_*8);         // ex(n)
    const float* exm = EXB + (sel^1)*(B_*8);     // ex(n-1)
    float* lh1o = LH1 + sel*S_;   float* lh1n = LH1 + (sel^1)*S_;
    float* lc1o = LC1 + sel*S_;   float* lc1n = LC1 + (sel^1)*S_;
    float* lh2o = LH2 + sel*S_;   float* lh2n = LH2 + (sel^1)*S_;  // lh2o == lh2n(n-1)
    float* lc2o = LC2 + sel*S_;   float* lc2n = LC2 + (sel^1)*S_;

    // ===== P_A =====
    if (slot < 16) {
      if (n < T_) {
        const int rt = slot & 1, cq = slot >> 1;          // cq 0..7 (256-col quads)
        const int r0 = rows0 + rt*64;
        const int cell = cq >> 2;
        const float* hin = cell ? lh1o : GH1C;
#pragma unroll
        for (int half = 0; half < 2; ++half) {
          const int ct0 = cq*256 + half*128;
          GateEpiM epi{ cell ? lc1o : GC1C,
                        cell ? lh1n : GH1P,
                        cell ? lc1n : GC1P,
                        BG1P, r0, ct0, ((ct0 & 1023) >> 6) << 4 };
          mm_h<8,1,true>(sAB, sWe, sE, hin, nullptr,
                         WG1PK + (size_t)(ct0 >> 4)*512, 128*512,
                         WE1, 2048, ex, r0, ct0, epi);
        }
      }
    } else if (n >= 1) {
      const int s2 = slot - 16;
      const int rt = s2 & 1, ct = s2 >> 1;                // ct 0..7
      const int r0 = rows0 + rt*64, ct0 = ct*128;
      GateEpiM epi{ GC2C, GH2P, GC2P, BG2P, r0, ct0, (ct0 >> 6) << 4 };
      mm_h<16,2,false>(sAB, sWe, sE, GH1C, GH2C,
                       WG2PK + (size_t)(ct0 >> 4)*512, 64*512,
                       nullptr, 0, nullptr, r0, ct0, epi);
    }
    gbar_x(arr, slot, ++ep);

    // ===== P_B =====
    if (slot < 16) {
      if (n < T_) {
        const int rt = slot & 1, q = slot >> 1;
        const int ct = q & 3, kh = q >> 2;
        const int r0 = rows0 + rt*64, ct0 = ct*128;
        if (kh == 0) {
          MlpEpiM epi{ M1A, r0, ct0 };
          mm_h<16,2,false>(sAB, sWe, sE, GH1P, GC1P,
                           WP1PK + (size_t)(ct0 >> 4)*512, 32*512,
                           nullptr, 0, nullptr, r0, ct0, epi);
        } else {
          MlpEpiM epi{ M1B, r0, ct0 };
          mm_h<16,2,true>(sAB, sWe, sE, lh1n, lc1n,
                          WP1PK + (size_t)16*(32*512) + (size_t)(ct0 >> 4)*512, 32*512,
                          WEP1, 512, ex, r0, ct0, epi);
        }
      }
    } else if (n >= 1) {
      const int s2 = slot - 16;
      const int rt = s2 & 1, q = s2 >> 1;
      const int ct = q & 3, kh = q >> 2;
      const int r0 = rows0 + rt*64, ct0 = ct*128;
      if (kh == 0) {
        MlpEpiM epi{ M2A, r0, ct0 };
        mm_h<16,2,false>(sAB, sWe, sE, GH2P, GC2P,
                         WP2PK + (size_t)(ct0 >> 4)*512, 32*512,
                         nullptr, 0, nullptr, r0, ct0, epi);
      } else {
        MlpEpiM epi{ M2B, r0, ct0 };
        mm_h<16,2,true>(sAB, sWe, sE, lh2o, lc2o,      // lh2n(n-1), lc2n(n-1)
                        WP2PK + (size_t)16*(32*512) + (size_t)(ct0 >> 4)*512, 32*512,
                        WEP2, 512, exm, r0, ct0, epi);
      }
    }
    gbar_x(arr, slot, ++ep);

    // ===== P_C =====
    if (slot < 16) {
      if (n < T_) {
        const int rt = slot & 1, ct = slot >> 1;          // ct 0..7
        const int r0 = rows0 + rt*64, ct0 = ct*128;
        GateEpiM epi{ lc2o, lh2n, lc2n, BL2P, r0, ct0, (ct0 >> 6) << 4 };
        mm_h<16,2,false>(sAB, sWe, sE, lh1n, lh2o,
                         WL2PK + (size_t)(ct0 >> 4)*512, 64*512,
                         nullptr, 0, nullptr, r0, ct0, epi);
      }
    } else if (slot < 24) {
      if (n < T_) {
        const int rb = rows0 + (slot-16)*16;
        stage_F2(rb, M1A, M1B, in.p1_b1, WB1, in.p1_b2, in.p1_W3, in.p1_b3,
                 lh1n, lc1n, GH1P, GC1P, GH1C, GC1C);
        if (n + 1 < T_ && threadIdx.x < 128) {
          const int r = rb + (threadIdx.x >> 3), j = threadIdx.x & 7;
          EXB[(sel^1)*(B_*8) + r*8 + j] =
              in.emb[(size_t)in.seq[(size_t)r*T_ + n + 1]*8 + j];
        }
      }
    } else {
      if (n >= 1) {
        const int rb = rows0 + (slot-24)*16;
        stage_F2(rb, M2A, M2B, in.p2_b1, WB2, in.p2_b2, in.p2_W3, in.p2_b3,
                 lh2o, lc2o, GH2P, GC2P, GH2C, GC2C);
        __syncthreads();
        stage_OUT2(GH2C, WOUT, BOUT, out, rb, n-1);
      }
    }
    gbar_x(arr, slot, ++ep);
  }
}

// ---------------- host ----------------
extern "C" void kernel_launch(void* const* d_in, const int* in_sizes, int n_in,
                              void* d_out, int out_size, void* d_ws, size_t ws_size,
                              hipStream_t stream)
{
  if (ws_size < WS_FLOATS * sizeof(float)) return;

  InP in;
  in.seq    = (const int*)  d_in[0];
  in.emb    = (const float*)d_in[1];
  in.g1_Wih = (const float*)d_in[2];  in.g1_Whh = (const float*)d_in[3];
  in.g1_bih = (const float*)d_in[4];  in.g1_bhh = (const float*)d_in[5];
  in.g2_Wih = (const float*)d_in[6];  in.g2_Whh = (const float*)d_in[7];
  in.g2_bih = (const float*)d_in[8];  in.g2_bhh = (const float*)d_in[9];
  in.l1_Wih = (const float*)d_in[10]; in.l1_Whh = (const float*)d_in[11];
  in.l1_bih = (const float*)d_in[12]; in.l1_bhh = (const float*)d_in[13];
  in.l2_Wih = (const float*)d_in[14]; in.l2_Whh = (const float*)d_in[15];
  in.l2_bih = (const float*)d_in[16]; in.l2_bhh = (const float*)d_in[17];
  in.p1_W1  = (const float*)d_in[18]; in.p1_b1  = (const float*)d_in[19];
  in.p1_W2  = (const float*)d_in[20]; in.p1_b2  = (const float*)d_in[21];
  in.p1_W3  = (const float*)d_in[22]; in.p1_b3  = (const float*)d_in[23];
  in.p2_W1  = (const float*)d_in[24]; in.p2_b1  = (const float*)d_in[25];
  in.p2_W2  = (const float*)d_in[26]; in.p2_b2  = (const float*)d_in[27];
  in.p2_W3  = (const float*)d_in[28]; in.p2_b3  = (const float*)d_in[29];
  in.gfc_W  = (const float*)d_in[30]; in.gfc_b  = (const float*)d_in[31];
  in.lfc_W  = (const float*)d_in[32]; in.lfc_b  = (const float*)d_in[33];

  float* ws  = (float*)d_ws;
  float* out = (float*)d_out;

  k_setup<<<512, 256, 0, stream>>>(in, ws);
  k_main <<<NBLK, NTHR, 53248, stream>>>(in, ws, out);   // dyn LDS: 1 block/CU pin
}